// Round 2
// baseline (780.567 us; speedup 1.0000x reference)
//
#include <hip/hip_runtime.h>

#define N_ATOMS 10000
#define N_EDGES 160000
#define N_STRUCT 8
#define D_PAD 48             // padded slots per atom; P(Poisson(16) > 48) ~ 2e-7 overall
#define EDW 48               // floats per slot: [0..15]=sh, [16..31]=R, [32..47]=hs
#define N_SLOTS (N_ATOMS * D_PAD)
#define PI_F 3.14159265358979323846f

#define CHUNK 12                     // slots per staged chunk
#define CEDW (CHUNK * EDW)           // 576 floats per chunk (2304 B)
#define WREG (2 * CEDW)              // 1152 floats per wave (double buffer)

// async global->LDS DMA, verified widths only (16B and 4B per lane)
__device__ __forceinline__ void load_lds16(const float* g, float* l) {
    __builtin_amdgcn_global_load_lds(
        (const __attribute__((address_space(1))) void*)g,
        (__attribute__((address_space(3))) void*)l,
        16, 0, 0);
}
__device__ __forceinline__ void load_lds4(const float* g, float* l) {
    __builtin_amdgcn_global_load_lds(
        (const __attribute__((address_space(1))) void*)g,
        (__attribute__((address_space(3))) void*)l,
        4, 0, 0);
}

// ---------------- setup ----------------

__global__ void init_kernel(float* __restrict__ edat, int* __restrict__ snd,
                            int* __restrict__ cursor, float* __restrict__ accum) {
    int i = blockIdx.x * blockDim.x + threadIdx.x;
    if (i < N_SLOTS) {
        float4 z = make_float4(0.f, 0.f, 0.f, 0.f);
        float4* p = (float4*)(edat + (size_t)i * EDW);
        p[0] = z; p[1] = z; p[2] = z; p[3] = z;
        snd[i] = 0;
    }
    if (i < N_ATOMS) cursor[i] = i * D_PAD;
    if (i < N_STRUCT) accum[i] = 0.f;
}

__global__ void scatter_kernel(const int* __restrict__ receivers, int* __restrict__ cursor,
                               int* __restrict__ perm) {
    int e = blockIdx.x * blockDim.x + threadIdx.x;
    if (e < N_EDGES) perm[e] = atomicAdd(&cursor[receivers[e]], 1);
}

__global__ void emb_kernel(const float* __restrict__ embed, const int* __restrict__ species,
                           float* __restrict__ h0) {
    int i = blockIdx.x * blockDim.x + threadIdx.x;
    if (i < N_ATOMS * 16) {
        int a = i >> 4, c = i & 15;
        h0[i] = embed[species[a] * 16 + c];
    }
}

__global__ void gather_h(const int* __restrict__ snd, const float* __restrict__ h,
                         float* __restrict__ edat) {
    int g = blockIdx.x * blockDim.x + threadIdx.x;
    if (g < N_SLOTS * 4) {
        int slot = g >> 2, seg = g & 3;
        int s = snd[slot];
        *(float4*)(edat + (size_t)slot * EDW + 32 + seg * 4) =
            *(const float4*)(h + (size_t)s * 16 + seg * 4);
    }
}

// transpose W_inv [256,16] -> W_invT [16,256] so the per-wave epilogue matmul
// reads contiguous float4 rows (both layers in one tiny launch)
__global__ void transpose_winv(const float* __restrict__ A, const float* __restrict__ B,
                               float* __restrict__ AT, float* __restrict__ BT) {
    int i = blockIdx.x * blockDim.x + threadIdx.x;
    if (i < 4096) {
        int k = i >> 4, c = i & 15;
        AT[c * 256 + k] = A[i];
    } else if (i < 8192) {
        int j = i - 4096;
        int k = j >> 4, c = j & 15;
        BT[c * 256 + k] = B[j];
    }
}

// ---------------- edge geometry -> padded slots ----------------

__global__ void edge_geom(const float* __restrict__ pos, const float* __restrict__ W_rad,
                          const int* __restrict__ senders, const int* __restrict__ receivers,
                          const int* __restrict__ perm,
                          float* __restrict__ edat, int* __restrict__ snd) {
    int e = blockIdx.x * blockDim.x + threadIdx.x;
    if (e >= N_EDGES) return;
    int s = senders[e], rc = receivers[e];
    int p = perm[e];
    float dx = pos[rc * 3 + 0] - pos[s * 3 + 0];
    float dy = pos[rc * 3 + 1] - pos[s * 3 + 1];
    float dz = pos[rc * 3 + 2] - pos[s * 3 + 2];
    float r = sqrtf(dx * dx + dy * dy + dz * dz);
    float rr = fmaxf(r, 1e-6f);
    float inv = 1.0f / rr;
    float x = dx * inv, y = dy * inv, z = dz * inv;
    float x2 = x * x, y2 = y * y, z2 = z * z;
    float she[16];
    she[0]  = 0.28209479f;
    she[1]  = 0.48860251f * y;
    she[2]  = 0.48860251f * z;
    she[3]  = 0.48860251f * x;
    she[4]  = 1.09254843f * x * y;
    she[5]  = 1.09254843f * y * z;
    she[6]  = 0.31539157f * (3.0f * z2 - 1.0f);
    she[7]  = 1.09254843f * x * z;
    she[8]  = 0.54627422f * (x2 - y2);
    she[9]  = 0.59004359f * y * (3.0f * x2 - y2);
    she[10] = 2.89061144f * x * y * z;
    she[11] = 0.45704579f * y * (5.0f * z2 - 1.0f);
    she[12] = 0.37317633f * z * (5.0f * z2 - 3.0f);
    she[13] = 0.45704579f * x * (5.0f * z2 - 1.0f);
    she[14] = 1.44530572f * z * (x2 - y2);
    she[15] = 0.59004359f * x * (x2 - 3.0f * y2);
    float* ed = edat + (size_t)p * EDW;
    ((float4*)ed)[0] = make_float4(she[0], she[1], she[2], she[3]);
    ((float4*)ed)[1] = make_float4(she[4], she[5], she[6], she[7]);
    ((float4*)ed)[2] = make_float4(she[8], she[9], she[10], she[11]);
    ((float4*)ed)[3] = make_float4(she[12], she[13], she[14], she[15]);
    float fc = 0.5f * (cosf(PI_F * fminf(r * 0.2f, 1.0f)) + 1.0f);
    const float c0 = 0.6324555320336759f; // sqrt(2/5)
    float bfv[8];
    #pragma unroll
    for (int n = 0; n < 8; ++n)
        bfv[n] = c0 * sinf((float)(n + 1) * PI_F * rr * 0.2f) * inv * fc;
    float Re[16];
    #pragma unroll
    for (int l = 0; l < 4; ++l) {
        #pragma unroll
        for (int n = 0; n < 4; ++n) {
            float acc = 0.0f;
            #pragma unroll
            for (int b = 0; b < 8; ++b) acc = fmaf(bfv[b], W_rad[l * 32 + b * 4 + n], acc);
            Re[l * 4 + n] = acc;
        }
    }
    ((float4*)ed)[4] = make_float4(Re[0], Re[1], Re[2], Re[3]);
    ((float4*)ed)[5] = make_float4(Re[4], Re[5], Re[6], Re[7]);
    ((float4*)ed)[6] = make_float4(Re[8], Re[9], Re[10], Re[11]);
    ((float4*)ed)[7] = make_float4(Re[12], Re[13], Re[14], Re[15]);
    snd[p] = s;
}

// ---------------- fused MP layer: one wave per atom ----------------
// Chunked double-buffered LDS-DMA: 4 chunks x 12 slots, each staged with
// HW-verified widths (2 x 16B-lane + 1 x 4B-lane = 2304 B, 3 VMEM ops).
// Counted vmcnt(3) waits: next chunk's HBM transfer overlaps compute (T3/T4).
// lgkmcnt(0)+sched_barrier fence before re-staging a just-read buffer.
// 128-thread blocks (2 waves / 2 atoms), 9216 B LDS -> 16 blocks = 32 waves/CU.
// Waves fully independent: per-wave epilogue via W_invT + shfl reduce, no barriers.

__global__ __launch_bounds__(128, 8) void mp_layer(
    const float* __restrict__ edat,
    const float* __restrict__ W_invT,
    const float* __restrict__ cemb, float* __restrict__ h_out,
    const float* __restrict__ w_out, const float* __restrict__ comp_w,
    const int* __restrict__ species, const int* __restrict__ sids,
    float* __restrict__ accum, int do_energy)
{
    __shared__ __attribute__((aligned(16))) float lds[2][WREG]; // 1152 f/wave, 9216 B/block
    // per-wave region: [0..575]=buf0, [576..1151]=buf1 (staging)
    // epilogue (staging dead, all DMA drained): s_A -> [0..1083], s_inv -> [0..255]

    const int t = threadIdx.x;
    const int w = t >> 6, lane = t & 63;
    const int atom = blockIdx.x * 2 + w;               // 5000*2 == 10000 exactly
    const int m = lane >> 2, cg = lane & 3;
    const int l = (m >= 9) ? 3 : (m >= 4) ? 2 : (m >= 1) ? 1 : 0;
    const int l4 = l * 4, cg4 = cg * 4;

    const float* gsrc = edat + (size_t)atom * (D_PAD * EDW);
    float* buf0 = &lds[w][0];
    float* buf1 = &lds[w][CEDW];

    auto stage = [&](int ch, float* dst) {
        const float* gs = gsrc + ch * CEDW;
        load_lds16(gs + lane * 4,       dst);        // 1024 B -> floats [0..255]
        load_lds16(gs + 256 + lane * 4, dst + 256);  // 1024 B -> floats [256..511]
        load_lds4 (gs + 512 + lane,     dst + 512);  //  256 B -> floats [512..575]
    };

    float acc[4][4];  // [n][j]
    #pragma unroll
    for (int n = 0; n < 4; ++n)
        #pragma unroll
        for (int j = 0; j < 4; ++j) acc[n][j] = 0.f;

    auto compute12 = [&](const float* bb) {
        #pragma unroll
        for (int q = 0; q < CHUNK; ++q) {
            const float* eq = bb + q * EDW;
            float shv = eq[m];
            float4 rv = *(const float4*)(eq + 16 + l4);
            float4 hv = *(const float4*)(eq + 32 + cg4);
            float hvj[4] = {hv.x, hv.y, hv.z, hv.w};
            float rvn[4] = {rv.x, rv.y, rv.z, rv.w};
            #pragma unroll
            for (int j = 0; j < 4; ++j) {
                float ww = shv * hvj[j];
                #pragma unroll
                for (int n = 0; n < 4; ++n)
                    acc[n][j] = fmaf(ww, rvn[n], acc[n][j]);
            }
        }
    };

    // ---- software pipeline: prefetch depth 1 chunk, vmcnt never drained mid-loop ----
    stage(0, buf0);
    stage(1, buf1);
    __builtin_amdgcn_s_waitcnt(0x0F73);   // vmcnt(3): chunk0 landed, chunk1 in flight
    __builtin_amdgcn_sched_barrier(0);
    compute12(buf0);

    __builtin_amdgcn_sched_barrier(0);
    __builtin_amdgcn_s_waitcnt(0xC07F);   // lgkmcnt(0): buf0 reads retired before DMA reuse
    __builtin_amdgcn_sched_barrier(0);
    stage(2, buf0);
    __builtin_amdgcn_s_waitcnt(0x0F73);   // vmcnt(3): chunk1 landed, chunk2 in flight
    __builtin_amdgcn_sched_barrier(0);
    compute12(buf1);

    __builtin_amdgcn_sched_barrier(0);
    __builtin_amdgcn_s_waitcnt(0xC07F);   // lgkmcnt(0): buf1 reads retired before DMA reuse
    __builtin_amdgcn_sched_barrier(0);
    stage(3, buf1);
    __builtin_amdgcn_s_waitcnt(0x0F73);   // vmcnt(3): chunk2 landed, chunk3 in flight
    __builtin_amdgcn_sched_barrier(0);
    compute12(buf0);

    __builtin_amdgcn_s_waitcnt(0x0F70);   // vmcnt(0): chunk3 landed (tail only)
    __builtin_amdgcn_sched_barrier(0);
    compute12(buf1);

    // ---- A -> LDS (aliases dead staging buffers; same-wave DS is in-order) ----
    float* s_A = &lds[w][0];
    #pragma unroll
    for (int n = 0; n < 4; ++n)
        *(float4*)&s_A[m * 68 + n * 16 + cg4] =
            make_float4(acc[n][0], acc[n][1], acc[n][2], acc[n][3]);

    const float sc_l[4] = {1.0f, 0.57735026918962576f, 0.44721359549995794f, 0.37796447300922720f};
    float inv4[4];
    #pragma unroll
    for (int i = 0; i < 4; ++i) {
        const int kt = lane * 4 + i;
        const int le = kt >> 6, k64 = kt & 63;
        const int m0 = le * le, m1 = m0 + 2 * le;
        float s = 0.f;
        for (int mm = m0; mm <= m1; ++mm) {
            float v = s_A[mm * 68 + k64];
            s = fmaf(v, v, s);
        }
        inv4[i] = s * sc_l[le];
    }

    if (do_energy) {
        float s = 0.f;
        #pragma unroll
        for (int i = 0; i < 4; ++i) s = fmaf(inv4[i], w_out[lane * 4 + i], s);
        #pragma unroll
        for (int off = 32; off > 0; off >>= 1) s += __shfl_down(s, off);
        if (lane == 0) atomicAdd(&accum[sids[atom]], s + comp_w[species[atom]]);
    } else {
        // per-wave h_new = (inv @ W_inv) * cemb, no cross-wave traffic
        *(float4*)&lds[w][lane * 4] = make_float4(inv4[0], inv4[1], inv4[2], inv4[3]);
        const int c = lane & 15, q4 = lane >> 4;     // lane covers (c, k-quarter q4)
        const float* wrow = W_invT + c * 256 + q4 * 64;
        float p = 0.f;
        #pragma unroll
        for (int kk = 0; kk < 16; ++kk) {
            float4 iv = *(const float4*)&lds[w][q4 * 64 + kk * 4];
            float4 wv = *(const float4*)(wrow + kk * 4);
            p = fmaf(iv.x, wv.x, p);
            p = fmaf(iv.y, wv.y, p);
            p = fmaf(iv.z, wv.z, p);
            p = fmaf(iv.w, wv.w, p);
        }
        p += __shfl_xor(p, 16);
        p += __shfl_xor(p, 32);
        if (lane < 16) h_out[atom * 16 + c] = p * cemb[atom * 16 + c];
    }
}

__global__ void out_kernel(const float* __restrict__ accum, float* __restrict__ out) {
    int t = threadIdx.x;
    if (t < N_STRUCT) out[t] = accum[t];
}

// ---------------- launch ----------------

extern "C" void kernel_launch(void* const* d_in, const int* in_sizes, int n_in,
                              void* d_out, int out_size, void* d_ws, size_t ws_size,
                              hipStream_t stream) {
    const float* positions = (const float*)d_in[0];
    const float* embed     = (const float*)d_in[1];
    const float* W_rad     = (const float*)d_in[2];
    const float* W_inv1    = (const float*)d_in[3];
    const float* W_inv2    = (const float*)d_in[4];
    const float* w_out     = (const float*)d_in[5];
    const float* comp_w    = (const float*)d_in[6];
    const int* senders    = (const int*)d_in[7];
    const int* receivers  = (const int*)d_in[8];
    const int* species    = (const int*)d_in[9];
    const int* sids       = (const int*)d_in[10];
    float* out = (float*)d_out;

    char* ws = (char*)d_ws;
    size_t off = 0;
    auto alloc = [&](size_t bytes) -> void* {
        void* p = ws + off;
        off = (off + bytes + 255) & ~(size_t)255;
        return p;
    };
    float* edat     = (float*)alloc((size_t)N_SLOTS * EDW * 4);   // 92.2 MB
    float* h0       = (float*)alloc((size_t)N_ATOMS * 16 * 4);
    float* h1       = (float*)alloc((size_t)N_ATOMS * 16 * 4);
    int*   cursor   = (int*)alloc((size_t)N_ATOMS * 4);
    int*   perm     = (int*)alloc((size_t)N_EDGES * 4);
    int*   snd      = (int*)alloc((size_t)N_SLOTS * 4);
    float* accum    = (float*)alloc(8 * 4);
    float* WT1      = (float*)alloc(4096 * 4);
    float* WT2      = (float*)alloc(4096 * 4);

    const int EB = (N_EDGES + 255) / 256;        // 625
    const int HB = (N_ATOMS * 16 + 255) / 256;   // 625
    const int IB = (N_SLOTS + 255) / 256;        // 1875
    const int GB = (N_SLOTS * 4 + 255) / 256;    // 7500

    init_kernel<<<IB, 256, 0, stream>>>(edat, snd, cursor, accum);
    scatter_kernel<<<EB, 256, 0, stream>>>(receivers, cursor, perm);
    edge_geom<<<EB, 256, 0, stream>>>(positions, W_rad, senders, receivers, perm,
                                      edat, snd);
    emb_kernel<<<HB, 256, 0, stream>>>(embed, species, h0);
    transpose_winv<<<32, 256, 0, stream>>>(W_inv1, W_inv2, WT1, WT2);

    // layer 1
    gather_h<<<GB, 256, 0, stream>>>(snd, h0, edat);
    mp_layer<<<N_ATOMS / 2, 128, 0, stream>>>(edat, WT1, h0, h1,
                                              w_out, comp_w, species, sids, accum, 0);
    // layer 2 (energy)
    gather_h<<<GB, 256, 0, stream>>>(snd, h1, edat);
    mp_layer<<<N_ATOMS / 2, 128, 0, stream>>>(edat, WT2, h0, h1,
                                              w_out, comp_w, species, sids, accum, 1);

    out_kernel<<<1, 64, 0, stream>>>(accum, out);
}

// Round 3
// 311.847 us; speedup vs baseline: 2.5030x; 2.5030x over previous
//
#include <hip/hip_runtime.h>

#define N_ATOMS 10000
#define N_EDGES 160000
#define N_STRUCT 8
#define D_PAD 48             // padded slots per atom; P(Poisson(16) > 48) ~ 2e-7 overall
#define EDW 48               // floats per slot: [0..15]=sh, [16..31]=R, [32..47]=hs
#define N_SLOTS (N_ATOMS * D_PAD)
#define PI_F 3.14159265358979323846f

#define CHUNK 12                     // slots per staged chunk
#define CEDW (CHUNK * EDW)           // 576 floats per chunk (2304 B)
#define WREG (2 * CEDW)              // 1152 floats per wave (double buffer)

// async global->LDS DMA, verified widths only (16B and 4B per lane)
__device__ __forceinline__ void load_lds16(const float* g, float* l) {
    __builtin_amdgcn_global_load_lds(
        (const __attribute__((address_space(1))) void*)g,
        (__attribute__((address_space(3))) void*)l,
        16, 0, 0);
}
__device__ __forceinline__ void load_lds4(const float* g, float* l) {
    __builtin_amdgcn_global_load_lds(
        (const __attribute__((address_space(1))) void*)g,
        (__attribute__((address_space(3))) void*)l,
        4, 0, 0);
}

// ---------------- setup ----------------

__global__ void init_kernel(float* __restrict__ edat, int* __restrict__ snd,
                            int* __restrict__ cursor, float* __restrict__ accum) {
    int i = blockIdx.x * blockDim.x + threadIdx.x;
    if (i < N_SLOTS) {
        float4 z = make_float4(0.f, 0.f, 0.f, 0.f);
        float4* p = (float4*)(edat + (size_t)i * EDW);
        p[0] = z; p[1] = z; p[2] = z; p[3] = z;
        snd[i] = 0;
    }
    if (i < N_ATOMS) cursor[i] = i * D_PAD;
    if (i < N_STRUCT) accum[i] = 0.f;
}

__global__ void scatter_kernel(const int* __restrict__ receivers, int* __restrict__ cursor,
                               int* __restrict__ perm) {
    int e = blockIdx.x * blockDim.x + threadIdx.x;
    if (e < N_EDGES) perm[e] = atomicAdd(&cursor[receivers[e]], 1);
}

__global__ void emb_kernel(const float* __restrict__ embed, const int* __restrict__ species,
                           float* __restrict__ h0) {
    int i = blockIdx.x * blockDim.x + threadIdx.x;
    if (i < N_ATOMS * 16) {
        int a = i >> 4, c = i & 15;
        h0[i] = embed[species[a] * 16 + c];
    }
}

__global__ void gather_h(const int* __restrict__ snd, const float* __restrict__ h,
                         float* __restrict__ edat) {
    int g = blockIdx.x * blockDim.x + threadIdx.x;
    if (g < N_SLOTS * 4) {
        int slot = g >> 2, seg = g & 3;
        int s = snd[slot];
        *(float4*)(edat + (size_t)slot * EDW + 32 + seg * 4) =
            *(const float4*)(h + (size_t)s * 16 + seg * 4);
    }
}

// transpose W_inv [256,16] -> W_invT [16,256] so the per-wave epilogue matmul
// reads contiguous float4 rows (both layers in one tiny launch)
__global__ void transpose_winv(const float* __restrict__ A, const float* __restrict__ B,
                               float* __restrict__ AT, float* __restrict__ BT) {
    int i = blockIdx.x * blockDim.x + threadIdx.x;
    if (i < 4096) {
        int k = i >> 4, c = i & 15;
        AT[c * 256 + k] = A[i];
    } else if (i < 8192) {
        int j = i - 4096;
        int k = j >> 4, c = j & 15;
        BT[c * 256 + k] = B[j];
    }
}

// ---------------- edge geometry -> padded slots ----------------

__global__ void edge_geom(const float* __restrict__ pos, const float* __restrict__ W_rad,
                          const int* __restrict__ senders, const int* __restrict__ receivers,
                          const int* __restrict__ perm,
                          float* __restrict__ edat, int* __restrict__ snd) {
    int e = blockIdx.x * blockDim.x + threadIdx.x;
    if (e >= N_EDGES) return;
    int s = senders[e], rc = receivers[e];
    int p = perm[e];
    float dx = pos[rc * 3 + 0] - pos[s * 3 + 0];
    float dy = pos[rc * 3 + 1] - pos[s * 3 + 1];
    float dz = pos[rc * 3 + 2] - pos[s * 3 + 2];
    float r = sqrtf(dx * dx + dy * dy + dz * dz);
    float rr = fmaxf(r, 1e-6f);
    float inv = 1.0f / rr;
    float x = dx * inv, y = dy * inv, z = dz * inv;
    float x2 = x * x, y2 = y * y, z2 = z * z;
    float she[16];
    she[0]  = 0.28209479f;
    she[1]  = 0.48860251f * y;
    she[2]  = 0.48860251f * z;
    she[3]  = 0.48860251f * x;
    she[4]  = 1.09254843f * x * y;
    she[5]  = 1.09254843f * y * z;
    she[6]  = 0.31539157f * (3.0f * z2 - 1.0f);
    she[7]  = 1.09254843f * x * z;
    she[8]  = 0.54627422f * (x2 - y2);
    she[9]  = 0.59004359f * y * (3.0f * x2 - y2);
    she[10] = 2.89061144f * x * y * z;
    she[11] = 0.45704579f * y * (5.0f * z2 - 1.0f);
    she[12] = 0.37317633f * z * (5.0f * z2 - 3.0f);
    she[13] = 0.45704579f * x * (5.0f * z2 - 1.0f);
    she[14] = 1.44530572f * z * (x2 - y2);
    she[15] = 0.59004359f * x * (x2 - 3.0f * y2);
    float* ed = edat + (size_t)p * EDW;
    ((float4*)ed)[0] = make_float4(she[0], she[1], she[2], she[3]);
    ((float4*)ed)[1] = make_float4(she[4], she[5], she[6], she[7]);
    ((float4*)ed)[2] = make_float4(she[8], she[9], she[10], she[11]);
    ((float4*)ed)[3] = make_float4(she[12], she[13], she[14], she[15]);
    float fc = 0.5f * (cosf(PI_F * fminf(r * 0.2f, 1.0f)) + 1.0f);
    const float c0 = 0.6324555320336759f; // sqrt(2/5)
    float bfv[8];
    #pragma unroll
    for (int n = 0; n < 8; ++n)
        bfv[n] = c0 * sinf((float)(n + 1) * PI_F * rr * 0.2f) * inv * fc;
    float Re[16];
    #pragma unroll
    for (int l = 0; l < 4; ++l) {
        #pragma unroll
        for (int n = 0; n < 4; ++n) {
            float acc = 0.0f;
            #pragma unroll
            for (int b = 0; b < 8; ++b) acc = fmaf(bfv[b], W_rad[l * 32 + b * 4 + n], acc);
            Re[l * 4 + n] = acc;
        }
    }
    ((float4*)ed)[4] = make_float4(Re[0], Re[1], Re[2], Re[3]);
    ((float4*)ed)[5] = make_float4(Re[4], Re[5], Re[6], Re[7]);
    ((float4*)ed)[6] = make_float4(Re[8], Re[9], Re[10], Re[11]);
    ((float4*)ed)[7] = make_float4(Re[12], Re[13], Re[14], Re[15]);
    snd[p] = s;
}

// ---------------- fused MP layer: one wave per atom ----------------
// Chunked double-buffered LDS-DMA: 4 chunks x 12 slots, HW-verified DMA widths
// (2 x 16B-lane + 1 x 4B-lane = 2304 B, 3 VMEM ops). Counted vmcnt(3) waits
// keep the next chunk's HBM transfer in flight under compute (T3/T4).
// lgkmcnt(0)+sched_barrier fence before re-staging a just-read buffer.
// 128-thread blocks (2 waves / 2 atoms), 9216 B LDS.
// __launch_bounds__(128, 4): VGPR cap 128 -- R2's (128,8) cap forced a 32-VGPR
// allocation that spilled ~1.1 GB of scratch traffic per dispatch (WRITE_SIZE
// 700 MB). Let the allocator take ~64 regs; LDS still allows 16 blocks/CU.

__global__ __launch_bounds__(128, 4) void mp_layer(
    const float* __restrict__ edat,
    const float* __restrict__ W_invT,
    const float* __restrict__ cemb, float* __restrict__ h_out,
    const float* __restrict__ w_out, const float* __restrict__ comp_w,
    const int* __restrict__ species, const int* __restrict__ sids,
    float* __restrict__ accum, int do_energy)
{
    __shared__ __attribute__((aligned(16))) float lds[2][WREG]; // 1152 f/wave, 9216 B/block
    // per-wave region: [0..575]=buf0, [576..1151]=buf1 (staging)
    // epilogue (staging dead, all DMA drained): s_A -> [0..1083], s_inv -> [0..255]

    const int t = threadIdx.x;
    const int w = t >> 6, lane = t & 63;
    const int atom = blockIdx.x * 2 + w;               // 5000*2 == 10000 exactly
    const int m = lane >> 2, cg = lane & 3;
    const int l = (m >= 9) ? 3 : (m >= 4) ? 2 : (m >= 1) ? 1 : 0;
    const int l4 = l * 4, cg4 = cg * 4;

    const float* gsrc = edat + (size_t)atom * (D_PAD * EDW);
    float* buf0 = &lds[w][0];
    float* buf1 = &lds[w][CEDW];

    auto stage = [&](int ch, float* dst) {
        const float* gs = gsrc + ch * CEDW;
        load_lds16(gs + lane * 4,       dst);        // 1024 B -> floats [0..255]
        load_lds16(gs + 256 + lane * 4, dst + 256);  // 1024 B -> floats [256..511]
        load_lds4 (gs + 512 + lane,     dst + 512);  //  256 B -> floats [512..575]
    };

    float acc[4][4];  // [n][j]
    #pragma unroll
    for (int n = 0; n < 4; ++n)
        #pragma unroll
        for (int j = 0; j < 4; ++j) acc[n][j] = 0.f;

    auto compute12 = [&](const float* bb) {
        #pragma unroll
        for (int q = 0; q < CHUNK; ++q) {
            const float* eq = bb + q * EDW;
            float shv = eq[m];
            float4 rv = *(const float4*)(eq + 16 + l4);
            float4 hv = *(const float4*)(eq + 32 + cg4);
            float hvj[4] = {hv.x, hv.y, hv.z, hv.w};
            float rvn[4] = {rv.x, rv.y, rv.z, rv.w};
            #pragma unroll
            for (int j = 0; j < 4; ++j) {
                float ww = shv * hvj[j];
                #pragma unroll
                for (int n = 0; n < 4; ++n)
                    acc[n][j] = fmaf(ww, rvn[n], acc[n][j]);
            }
        }
    };

    // ---- software pipeline: prefetch depth 1 chunk, vmcnt never drained mid-loop ----
    stage(0, buf0);
    stage(1, buf1);
    __builtin_amdgcn_s_waitcnt(0x0F73);   // vmcnt(3): chunk0 landed, chunk1 in flight
    __builtin_amdgcn_sched_barrier(0);
    compute12(buf0);

    __builtin_amdgcn_sched_barrier(0);
    __builtin_amdgcn_s_waitcnt(0xC07F);   // lgkmcnt(0): buf0 reads retired before DMA reuse
    __builtin_amdgcn_sched_barrier(0);
    stage(2, buf0);
    __builtin_amdgcn_s_waitcnt(0x0F73);   // vmcnt(3): chunk1 landed, chunk2 in flight
    __builtin_amdgcn_sched_barrier(0);
    compute12(buf1);

    __builtin_amdgcn_sched_barrier(0);
    __builtin_amdgcn_s_waitcnt(0xC07F);   // lgkmcnt(0): buf1 reads retired before DMA reuse
    __builtin_amdgcn_sched_barrier(0);
    stage(3, buf1);
    __builtin_amdgcn_s_waitcnt(0x0F73);   // vmcnt(3): chunk2 landed, chunk3 in flight
    __builtin_amdgcn_sched_barrier(0);
    compute12(buf0);

    __builtin_amdgcn_s_waitcnt(0x0F70);   // vmcnt(0): chunk3 landed (tail only)
    __builtin_amdgcn_sched_barrier(0);
    compute12(buf1);

    // ---- A -> LDS (aliases dead staging buffers; same-wave DS is in-order) ----
    float* s_A = &lds[w][0];
    #pragma unroll
    for (int n = 0; n < 4; ++n)
        *(float4*)&s_A[m * 68 + n * 16 + cg4] =
            make_float4(acc[n][0], acc[n][1], acc[n][2], acc[n][3]);

    const float sc_l[4] = {1.0f, 0.57735026918962576f, 0.44721359549995794f, 0.37796447300922720f};
    float inv4[4];
    #pragma unroll
    for (int i = 0; i < 4; ++i) {
        const int kt = lane * 4 + i;
        const int le = kt >> 6, k64 = kt & 63;
        const int m0 = le * le, m1 = m0 + 2 * le;
        float s = 0.f;
        for (int mm = m0; mm <= m1; ++mm) {
            float v = s_A[mm * 68 + k64];
            s = fmaf(v, v, s);
        }
        inv4[i] = s * sc_l[le];
    }

    if (do_energy) {
        float s = 0.f;
        #pragma unroll
        for (int i = 0; i < 4; ++i) s = fmaf(inv4[i], w_out[lane * 4 + i], s);
        #pragma unroll
        for (int off = 32; off > 0; off >>= 1) s += __shfl_down(s, off);
        if (lane == 0) atomicAdd(&accum[sids[atom]], s + comp_w[species[atom]]);
    } else {
        // per-wave h_new = (inv @ W_inv) * cemb, no cross-wave traffic
        *(float4*)&lds[w][lane * 4] = make_float4(inv4[0], inv4[1], inv4[2], inv4[3]);
        const int c = lane & 15, q4 = lane >> 4;     // lane covers (c, k-quarter q4)
        const float* wrow = W_invT + c * 256 + q4 * 64;
        float p = 0.f;
        #pragma unroll
        for (int kk = 0; kk < 16; ++kk) {
            float4 iv = *(const float4*)&lds[w][q4 * 64 + kk * 4];
            float4 wv = *(const float4*)(wrow + kk * 4);
            p = fmaf(iv.x, wv.x, p);
            p = fmaf(iv.y, wv.y, p);
            p = fmaf(iv.z, wv.z, p);
            p = fmaf(iv.w, wv.w, p);
        }
        p += __shfl_xor(p, 16);
        p += __shfl_xor(p, 32);
        if (lane < 16) h_out[atom * 16 + c] = p * cemb[atom * 16 + c];
    }
}

__global__ void out_kernel(const float* __restrict__ accum, float* __restrict__ out) {
    int t = threadIdx.x;
    if (t < N_STRUCT) out[t] = accum[t];
}

// ---------------- launch ----------------

extern "C" void kernel_launch(void* const* d_in, const int* in_sizes, int n_in,
                              void* d_out, int out_size, void* d_ws, size_t ws_size,
                              hipStream_t stream) {
    const float* positions = (const float*)d_in[0];
    const float* embed     = (const float*)d_in[1];
    const float* W_rad     = (const float*)d_in[2];
    const float* W_inv1    = (const float*)d_in[3];
    const float* W_inv2    = (const float*)d_in[4];
    const float* w_out     = (const float*)d_in[5];
    const float* comp_w    = (const float*)d_in[6];
    const int* senders    = (const int*)d_in[7];
    const int* receivers  = (const int*)d_in[8];
    const int* species    = (const int*)d_in[9];
    const int* sids       = (const int*)d_in[10];
    float* out = (float*)d_out;

    char* ws = (char*)d_ws;
    size_t off = 0;
    auto alloc = [&](size_t bytes) -> void* {
        void* p = ws + off;
        off = (off + bytes + 255) & ~(size_t)255;
        return p;
    };
    float* edat     = (float*)alloc((size_t)N_SLOTS * EDW * 4);   // 92.2 MB
    float* h0       = (float*)alloc((size_t)N_ATOMS * 16 * 4);
    float* h1       = (float*)alloc((size_t)N_ATOMS * 16 * 4);
    int*   cursor   = (int*)alloc((size_t)N_ATOMS * 4);
    int*   perm     = (int*)alloc((size_t)N_EDGES * 4);
    int*   snd      = (int*)alloc((size_t)N_SLOTS * 4);
    float* accum    = (float*)alloc(8 * 4);
    float* WT1      = (float*)alloc(4096 * 4);
    float* WT2      = (float*)alloc(4096 * 4);

    const int EB = (N_EDGES + 255) / 256;        // 625
    const int HB = (N_ATOMS * 16 + 255) / 256;   // 625
    const int IB = (N_SLOTS + 255) / 256;        // 1875
    const int GB = (N_SLOTS * 4 + 255) / 256;    // 7500

    init_kernel<<<IB, 256, 0, stream>>>(edat, snd, cursor, accum);
    scatter_kernel<<<EB, 256, 0, stream>>>(receivers, cursor, perm);
    edge_geom<<<EB, 256, 0, stream>>>(positions, W_rad, senders, receivers, perm,
                                      edat, snd);
    emb_kernel<<<HB, 256, 0, stream>>>(embed, species, h0);
    transpose_winv<<<32, 256, 0, stream>>>(W_inv1, W_inv2, WT1, WT2);

    // layer 1
    gather_h<<<GB, 256, 0, stream>>>(snd, h0, edat);
    mp_layer<<<N_ATOMS / 2, 128, 0, stream>>>(edat, WT1, h0, h1,
                                              w_out, comp_w, species, sids, accum, 0);
    // layer 2 (energy)
    gather_h<<<GB, 256, 0, stream>>>(snd, h1, edat);
    mp_layer<<<N_ATOMS / 2, 128, 0, stream>>>(edat, WT2, h0, h1,
                                              w_out, comp_w, species, sids, accum, 1);

    out_kernel<<<1, 64, 0, stream>>>(accum, out);
}